// Round 5
// baseline (293.476 us; speedup 1.0000x reference)
//
#include <hip/hip_runtime.h>

#define NWIN 1000
#define WIN  500
#define HID  30
#define ANC  7
#define BATCH 64
#define KS   75
#define PADH 37
#define OBASE_ELEMS (BATCH*ANC*NWIN*2)   // 896000

// k1 geometry: 21 chunks of 24 positions (504 padded; 500 real)
#define CK   24
#define NCK  21

// LDS float-offset map (flat array; epilogue overlays the front)
//   x [buf][c][24 pos][68]  : buf*3264 + (c*24+p)*68 + b     [0 .. 6527]
//   W [buf][24 pos][32]     : 6528 + buf*768 + p*32 + j      [6528 .. 8063]
//   hs[ph][64 b][61]        : (ph*64+b)*61 + col  (overlay)  [0 .. 7807]
#define XB(buf,c,p,b) ((buf)*3264 + ((c)*24+(p))*68 + (b))
#define WB(buf,p,j)   (6528 + (buf)*768 + (p)*32 + (j))
#define HS(ph,b,col)  (((ph)*64+(b))*61 + (col))

__device__ __forceinline__ void gload_lds16(const float* g, float* l) {
    __builtin_amdgcn_global_load_lds(
        (const __attribute__((address_space(1))) void*)g,
        (__attribute__((address_space(3))) void*)l, 16, 0, 0);
}

// ---------------------------------------------------------------------------
// Kernel 1 (v5): one block per window, 4 waves, register-tiled GEMM1.
// lane = (bq 0..15, jq 0..3): acc[4 b][8 j][2 c] (64 VGPR).
// Per position: 2 b128 W + 2 b128 x per 64 FMA; each position read by exactly
// one wave. W via global_load_lds into [p][32]; x reg-staged (6 float2).
// ---------------------------------------------------------------------------
__global__ __launch_bounds__(256, 4) void k1(
        const float* __restrict__ x,
        const float* __restrict__ W1, const float* __restrict__ b1,
        const float* __restrict__ W2, const float* __restrict__ b2,
        float* __restrict__ out_base)
{
    __shared__ float smem[8064];   // 32,256 B

    const int n    = blockIdx.x;
    const int t    = threadIdx.x;
    const int wid  = __builtin_amdgcn_readfirstlane(t >> 6);
    const int lane = t & 63;
    const int bq   = lane & 15;        // 4-batch group
    const int jq   = lane >> 4;        // j-quarter
    const int b0   = bq * 4;
    const int j0   = jq * 8;

    float acc[4][8][2];
#pragma unroll
    for (int i = 0; i < 4; ++i)
#pragma unroll
        for (int j = 0; j < 8; ++j) { acc[i][j][0] = 0.f; acc[i][j][1] = 0.f; }

    // staging coordinates: item r -> flat idx = t + r*256 over [b][24 pos]
    int sb[6], sp[6];
#pragma unroll
    for (int r = 0; r < 6; ++r) {
        const int idx = t + r * 256;
        sb[r] = idx / 24;
        sp[r] = idx % 24;
    }

    const float2* __restrict__ x2 = reinterpret_cast<const float2*>(x);
    float2 xr[6];

    auto issue_x = [&](int ck) {
#pragma unroll
        for (int r = 0; r < 6; ++r) {
            size_t flat = (size_t)sb[r] * 500000u + (size_t)n * 500u
                        + (size_t)ck * CK + sp[r];
            if (flat > 31999999u) flat = 31999999u;     // tail OOB clamp
            xr[r] = x2[flat];
        }
    };

    auto commit_x = [&](int buf, int ck) {
#pragma unroll
        for (int r = 0; r < 6; ++r) {
            const int gp = ck * CK + sp[r];
            const bool ok = gp < 500;
            const float f0 = ok ? fmaf(2.f, xr[r].x, -1.f) : 0.f;
            const float f1 = ok ? fmaf(2.f, xr[r].y, -1.f) : 0.f;
            smem[XB(buf, 0, sp[r], sb[r])] = f0;
            smem[XB(buf, 1, sp[r], sb[r])] = f1;
        }
    };

    // W chunk: 24 rows x 30 floats -> 192 16B granules into padded [24][32].
    // granule (row=t>>3, kq=t&7) reads floats row*30 + kq*4 (straddle junk
    // lands in pad slots 30/31 -> only touches never-used acc lanes).
    auto issue_w = [&](int ck, int buf) {
        if (t < 192) {
            size_t off = (size_t)n * 15000u + (size_t)(ck * CK + (t >> 3)) * 30u
                       + (size_t)(t & 7) * 4u;
            if (off > 14999996u) off = 14999996u;       // tail OOB clamp
            gload_lds16(W1 + off, &smem[WB(buf, 0, 0) + (t & 192) * 4]);
        }
    };

    // ---- prologue ------------------------------------------------------
    issue_w(0, 0);
    issue_x(0);
    commit_x(0, 0);
    __syncthreads();

    // ---- main loop: 1 barrier per chunk --------------------------------
    for (int ck = 0; ck < NCK; ++ck) {
        const int cur = ck & 1, nxt = cur ^ 1;
        const bool pre = (ck < NCK - 1);
        if (pre) {
            issue_w(ck + 1, nxt);
            issue_x(ck + 1);
            __builtin_amdgcn_sched_barrier(0);
        }

        const int pb = wid * 6;
#pragma unroll
        for (int i = 0; i < 6; ++i) {
            const int p = pb + i;
            const float4 xa = *reinterpret_cast<const float4*>(&smem[XB(cur, 0, p, b0)]);
            const float4 xb = *reinterpret_cast<const float4*>(&smem[XB(cur, 1, p, b0)]);
            const float4 w0 = *reinterpret_cast<const float4*>(&smem[WB(cur, p, j0)]);
            const float4 w1 = *reinterpret_cast<const float4*>(&smem[WB(cur, p, j0 + 4)]);
            const float xav[4] = {xa.x, xa.y, xa.z, xa.w};
            const float xbv[4] = {xb.x, xb.y, xb.z, xb.w};
            const float wv[8]  = {w0.x, w0.y, w0.z, w0.w, w1.x, w1.y, w1.z, w1.w};
#pragma unroll
            for (int ii = 0; ii < 4; ++ii)
#pragma unroll
                for (int jj = 0; jj < 8; ++jj) {
                    acc[ii][jj][0] = fmaf(xav[ii], wv[jj], acc[ii][jj][0]);
                    acc[ii][jj][1] = fmaf(xbv[ii], wv[jj], acc[ii][jj][1]);
                }
        }

        if (pre) commit_x(nxt, ck + 1);
        __syncthreads();
    }

    // ---- epilogue: reduce 4 wave-partials into hs[0] + hs[1] ------------
    if (wid < 2) {
#pragma unroll
        for (int ii = 0; ii < 4; ++ii)
#pragma unroll
            for (int jj = 0; jj < 8; ++jj) {
                const int j = j0 + jj;
                if (j < 30) {
                    smem[HS(wid, b0 + ii, j)]      = acc[ii][jj][0];
                    smem[HS(wid, b0 + ii, 30 + j)] = acc[ii][jj][1];
                }
            }
    }
    __syncthreads();
    if (wid >= 2) {
#pragma unroll
        for (int ii = 0; ii < 4; ++ii)
#pragma unroll
            for (int jj = 0; jj < 8; ++jj) {
                const int j = j0 + jj;
                if (j < 30) {
                    smem[HS(wid - 2, b0 + ii, j)]      += acc[ii][jj][0];
                    smem[HS(wid - 2, b0 + ii, 30 + j)] += acc[ii][jj][1];
                }
            }
    }
    __syncthreads();

    {   // bias + relu + batch stats (64-lane butterfly) + normalize
        const int bb = t & 63;
        const int q2 = t >> 6;
        const int ch = q2 >> 1;
        const int jh = (q2 & 1) * 15;
        const float* __restrict__ b1p = b1 + n * HID + jh;
#pragma unroll
        for (int jj = 0; jj < 15; ++jj) {
            const int col = ch * 30 + jh + jj;
            float v = smem[HS(0, bb, col)] + smem[HS(1, bb, col)] + b1p[jj];
            v = fmaxf(v, 0.f);
            float s = v, ss = v * v;
#pragma unroll
            for (int off = 32; off > 0; off >>= 1) {
                s  += __shfl_xor(s, off);
                ss += __shfl_xor(ss, off);
            }
            const float mean = s * (1.f / 64.f);
            const float var  = ss * (1.f / 64.f) - mean * mean;
            const float rn   = rsqrtf(var + 1e-5f);
            smem[HS(0, bb, col)] = (v - mean) * rn;
        }
    }
    __syncthreads();

    // ---- GEMM2 + write out_base[b][a][n][c] -----------------------------
    const float* __restrict__ w2p = W2 + (size_t)n * (HID * ANC);
    float2* __restrict__ ob2 = reinterpret_cast<float2*>(out_base);
    for (int idx = t; idx < BATCH * ANC; idx += 256) {
        const int bb = idx / 7, a = idx - bb * 7;
        float o0 = b2[n * ANC + a], o1 = o0;
#pragma unroll
        for (int h = 0; h < HID; ++h) {
            const float wv = w2p[h * ANC + a];
            o0 = fmaf(smem[HS(0, bb, h)],      wv, o0);
            o1 = fmaf(smem[HS(0, bb, 30 + h)], wv, o1);
        }
        ob2[((size_t)bb * ANC + a) * NWIN + n] = make_float2(o0, o1);
    }
}

// ---------------------------------------------------------------------------
// Kernel 2: softmax over ANC + reflect-pad + conv (2 needed output columns)
// via sum/diff factorization (unchanged).
// ---------------------------------------------------------------------------
__global__ __launch_bounds__(256, 2) void k2(
        const float* __restrict__ out_base,
        const float* __restrict__ conv_w, const float* __restrict__ conv_b,
        float* __restrict__ out_smooth)
{
    __shared__ float2 sdl[199 * ANC];
    __shared__ float2 wael[ANC * ANC * KS];

    const int bidx = blockIdx.x;
    const int b  = bidx >> 3;
    const int ht = bidx & 7;
    const int h0 = ht * 125;
    const int t  = threadIdx.x;

    const float2* __restrict__ cw2 = reinterpret_cast<const float2*>(conv_w);
    for (int idx = t; idx < ANC * ANC * KS; idx += 256) {
        const float2 w = cw2[idx];
        wael[idx] = make_float2(w.x + w.y, w.x - w.y);
    }

    if (t < 199) {
        const int hglob = h0 - PADH + t;
        const int hm = hglob < 0 ? -hglob
                     : (hglob >= NWIN ? 2 * NWIN - 2 - hglob : hglob);
        float p[2][ANC];
#pragma unroll
        for (int c = 0; c < 2; ++c) {
            float v[ANC];
            float m = -1e30f;
#pragma unroll
            for (int a = 0; a < ANC; ++a) {
                v[a] = out_base[(((size_t)b * ANC + a) * NWIN + hm) * 2 + c];
                m = fmaxf(m, v[a]);
            }
            float s = 0.f;
#pragma unroll
            for (int a = 0; a < ANC; ++a) { v[a] = __expf(v[a] - m); s += v[a]; }
            const float inv = 1.f / s;
#pragma unroll
            for (int a = 0; a < ANC; ++a) p[c][a] = v[a] * inv;
        }
#pragma unroll
        for (int a = 0; a < ANC; ++a)
            sdl[t * ANC + a] = make_float2(p[0][a] + p[1][a], p[0][a] - p[1][a]);
    }
    __syncthreads();

    for (int idx = t; idx < ANC * 125; idx += 256) {
        const int o  = idx / 125;
        const int hl = idx % 125;
        float sa = 0.f, de = 0.f;
        const float2* __restrict__ wrow = &wael[o * ANC * KS];
#pragma unroll 1
        for (int i = 0; i < ANC; ++i) {
            const float2* __restrict__ sdp = &sdl[hl * ANC + i];
            const float2* __restrict__ wp  = &wrow[i * KS];
#pragma unroll 5
            for (int kh = 0; kh < KS; ++kh) {
                const float2 sd = sdp[kh * ANC];
                const float2 we = wp[kh];
                sa = fmaf(sd.x, we.x, sa);
                de = fmaf(sd.y, we.y, de);
            }
        }
        const float cb = conv_b[o];
        const float o0 = 0.5f * (sa - de) + cb;
        const float o1 = 0.5f * (sa + de) + cb;
        const size_t base = (((size_t)b * ANC + o) * NWIN + (h0 + hl)) * 2;
        out_smooth[base + 0] = o0;
        out_smooth[base + 1] = o1;
    }
}

extern "C" void kernel_launch(void* const* d_in, const int* in_sizes, int n_in,
                              void* d_out, int out_size, void* d_ws, size_t ws_size,
                              hipStream_t stream)
{
    const float* x      = (const float*)d_in[0];
    const float* W1     = (const float*)d_in[1];
    const float* b1     = (const float*)d_in[2];
    const float* W2     = (const float*)d_in[3];
    const float* b2     = (const float*)d_in[4];
    const float* conv_w = (const float*)d_in[5];
    const float* conv_b = (const float*)d_in[6];
    float* out = (float*)d_out;

    k1<<<dim3(NWIN), dim3(256), 0, stream>>>(x, W1, b1, W2, b2, out);
    k2<<<dim3(BATCH * 8), dim3(256), 0, stream>>>(out, conv_w, conv_b,
                                                  out + OBASE_ELEMS);
}

// Round 6
// 166.866 us; speedup vs baseline: 1.7588x; 1.7588x over previous
//
#include <hip/hip_runtime.h>

#define NWIN 1000
#define WIN  500
#define HID  30
#define ANC  7
#define BATCH 64
#define KS   75
#define PADH 37
#define OBASE_ELEMS (BATCH*ANC*NWIN*2)   // 896000

// k1 geometry: 21 chunks of 24 positions (504 padded; 500 real)
#define CK   24
#define NCK  21

// LDS float-offset map (flat array; epilogue overlays the front)
//   x [buf][c][24 pos][68]  : buf*3264 + (c*24+p)*68 + b     [0 .. 6527]
//   W [buf][24 pos][32]     : 6528 + buf*768 + p*32 + j      [6528 .. 8063]
//   hs[ph][64 b][61]        : (ph*64+b)*61 + col  (overlay)  [0 .. 7807]
#define XB(buf,c,p,b) ((buf)*3264 + ((c)*24+(p))*68 + (b))
#define WB(buf,p,j)   (6528 + (buf)*768 + (p)*32 + (j))
#define HS(ph,b,col)  (((ph)*64+(b))*61 + (col))

__device__ __forceinline__ void gload_lds16(const float* g, float* l) {
    __builtin_amdgcn_global_load_lds(
        (const __attribute__((address_space(1))) void*)g,
        (__attribute__((address_space(3))) void*)l, 16, 0, 0);
}

// ---------------------------------------------------------------------------
// Kernel 1 (v6): v5 tile (LDS-instr-optimal) minus the spill triggers.
// lane = (bq 0..15, jq 0..3): acc[4 b][8 j][2 c]; per position one wave reads
// 2 b128 x + 2 b128 W for 64 FMA. W via global_load_lds (zero VGPR); x staged
// as 3 float4/thread (12 VGPR). launch_bounds(256,2) -> 256-reg budget.
// ---------------------------------------------------------------------------
__global__ __launch_bounds__(256, 2) void k1(
        const float* __restrict__ x,
        const float* __restrict__ W1, const float* __restrict__ b1,
        const float* __restrict__ W2, const float* __restrict__ b2,
        float* __restrict__ out_base)
{
    __shared__ float smem[8064];   // 32,256 B

    const int n    = blockIdx.x;
    const int t    = threadIdx.x;
    const int wid  = __builtin_amdgcn_readfirstlane(t >> 6);
    const int lane = t & 63;
    const int bq   = lane & 15;        // 4-batch group
    const int jq   = lane >> 4;        // j-quarter
    const int b0   = bq * 4;
    const int j0   = jq * 8;

    float acc[4][8][2];
#pragma unroll
    for (int i = 0; i < 4; ++i)
#pragma unroll
        for (int j = 0; j < 8; ++j) { acc[i][j][0] = 0.f; acc[i][j][1] = 0.f; }

    // x staging: granule = float4 = 2 positions x 2 channels.
    // 64 b * 12 granules = 768 per chunk -> exactly 3 per thread.
    int sb[3], sq[3];
#pragma unroll
    for (int r = 0; r < 3; ++r) {
        const int idx = t + r * 256;
        sb[r] = idx / 12;
        sq[r] = idx % 12;
    }

    const float4* __restrict__ x4 = reinterpret_cast<const float4*>(x);
    float4 xr[3];

    auto issue_x = [&](int ck) {
#pragma unroll
        for (int r = 0; r < 3; ++r) {
            int gq = ck * 12 + sq[r];          // float4 index within window row
            if (gq > 249) gq = 249;            // last-chunk OOB clamp
            xr[r] = x4[(size_t)sb[r] * 250000u + (size_t)n * 250u + gq];
        }
    };

    auto commit_x = [&](int buf, int ck) {
#pragma unroll
        for (int r = 0; r < 3; ++r) {
            const int p0 = 2 * sq[r], p1 = p0 + 1;
            const bool ok0 = (ck * CK + p0) < 500;
            const bool ok1 = (ck * CK + p1) < 500;
            const int bb = sb[r];
            smem[XB(buf, 0, p0, bb)] = ok0 ? fmaf(2.f, xr[r].x, -1.f) : 0.f;
            smem[XB(buf, 1, p0, bb)] = ok0 ? fmaf(2.f, xr[r].y, -1.f) : 0.f;
            smem[XB(buf, 0, p1, bb)] = ok1 ? fmaf(2.f, xr[r].z, -1.f) : 0.f;
            smem[XB(buf, 1, p1, bb)] = ok1 ? fmaf(2.f, xr[r].w, -1.f) : 0.f;
        }
    };

    // W chunk: 24 rows x 30 floats -> 192 16B granules into padded [24][32].
    // granule (row=t>>3, kq=t&7) reads floats row*30 + kq*4 (straddle junk
    // lands in pad slots 30/31 -> never used).
    auto issue_w = [&](int ck, int buf) {
        if (t < 192) {
            size_t off = (size_t)n * 15000u + (size_t)(ck * CK + (t >> 3)) * 30u
                       + (size_t)(t & 7) * 4u;
            if (off > 14999996u) off = 14999996u;       // tail OOB clamp
            gload_lds16(W1 + off, &smem[WB(buf, 0, 0) + (t & 192) * 4]);
        }
    };

    // ---- prologue ------------------------------------------------------
    issue_w(0, 0);
    issue_x(0);
    commit_x(0, 0);
    __syncthreads();

    // ---- main loop: 1 barrier per chunk --------------------------------
    for (int ck = 0; ck < NCK; ++ck) {
        const int cur = ck & 1, nxt = cur ^ 1;
        const bool pre = (ck < NCK - 1);
        if (pre) {
            issue_w(ck + 1, nxt);
            issue_x(ck + 1);
            __builtin_amdgcn_sched_barrier(0);   // pin issues before compute
        }

        const int pb = wid * 6;
#pragma unroll
        for (int i = 0; i < 6; ++i) {
            const int p = pb + i;
            const float4 xa = *reinterpret_cast<const float4*>(&smem[XB(cur, 0, p, b0)]);
            const float4 xb = *reinterpret_cast<const float4*>(&smem[XB(cur, 1, p, b0)]);
            const float4 w0 = *reinterpret_cast<const float4*>(&smem[WB(cur, p, j0)]);
            const float4 w1 = *reinterpret_cast<const float4*>(&smem[WB(cur, p, j0 + 4)]);
            const float xav[4] = {xa.x, xa.y, xa.z, xa.w};
            const float xbv[4] = {xb.x, xb.y, xb.z, xb.w};
            const float wv[8]  = {w0.x, w0.y, w0.z, w0.w, w1.x, w1.y, w1.z, w1.w};
#pragma unroll
            for (int ii = 0; ii < 4; ++ii)
#pragma unroll
                for (int jj = 0; jj < 8; ++jj) {
                    acc[ii][jj][0] = fmaf(xav[ii], wv[jj], acc[ii][jj][0]);
                    acc[ii][jj][1] = fmaf(xbv[ii], wv[jj], acc[ii][jj][1]);
                }
        }

        if (pre) commit_x(nxt, ck + 1);          // vmcnt waits (covered)
        __syncthreads();                         // drains gload_lds too
    }

    // ---- epilogue: reduce 4 wave-partials into hs[0] + hs[1] ------------
    if (wid < 2) {
#pragma unroll
        for (int ii = 0; ii < 4; ++ii)
#pragma unroll
            for (int jj = 0; jj < 8; ++jj) {
                const int j = j0 + jj;
                if (j < 30) {
                    smem[HS(wid, b0 + ii, j)]      = acc[ii][jj][0];
                    smem[HS(wid, b0 + ii, 30 + j)] = acc[ii][jj][1];
                }
            }
    }
    __syncthreads();
    if (wid >= 2) {
#pragma unroll
        for (int ii = 0; ii < 4; ++ii)
#pragma unroll
            for (int jj = 0; jj < 8; ++jj) {
                const int j = j0 + jj;
                if (j < 30) {
                    smem[HS(wid - 2, b0 + ii, j)]      += acc[ii][jj][0];
                    smem[HS(wid - 2, b0 + ii, 30 + j)] += acc[ii][jj][1];
                }
            }
    }
    __syncthreads();

    {   // bias + relu + TWO-PASS batch stats (64-lane butterflies) + normalize
        const int bb = t & 63;
        const int q2 = t >> 6;
        const int ch = q2 >> 1;
        const int jh = (q2 & 1) * 15;
        const float* __restrict__ b1p = b1 + n * HID + jh;
#pragma unroll
        for (int jj = 0; jj < 15; ++jj) {
            const int col = ch * 30 + jh + jj;
            float v = smem[HS(0, bb, col)] + smem[HS(1, bb, col)] + b1p[jj];
            v = fmaxf(v, 0.f);
            float s = v;
#pragma unroll
            for (int off = 32; off > 0; off >>= 1) s += __shfl_xor(s, off);
            const float mean = s * (1.f / 64.f);
            const float d = v - mean;
            float ss = d * d;
#pragma unroll
            for (int off = 32; off > 0; off >>= 1) ss += __shfl_xor(ss, off);
            const float var = ss * (1.f / 64.f);
            const float rn  = rsqrtf(var + 1e-5f);
            smem[HS(0, bb, col)] = d * rn;
        }
    }
    __syncthreads();

    // ---- GEMM2 + write out_base[b][a][n][c] -----------------------------
    const float* __restrict__ w2p = W2 + (size_t)n * (HID * ANC);
    float2* __restrict__ ob2 = reinterpret_cast<float2*>(out_base);
    for (int idx = t; idx < BATCH * ANC; idx += 256) {
        const int bb = idx / 7, a = idx - bb * 7;
        float o0 = b2[n * ANC + a], o1 = o0;
#pragma unroll
        for (int h = 0; h < HID; ++h) {
            const float wv = w2p[h * ANC + a];
            o0 = fmaf(smem[HS(0, bb, h)],      wv, o0);
            o1 = fmaf(smem[HS(0, bb, 30 + h)], wv, o1);
        }
        ob2[((size_t)bb * ANC + a) * NWIN + n] = make_float2(o0, o1);
    }
}

// ---------------------------------------------------------------------------
// Kernel 2: softmax over ANC + reflect-pad + conv (2 needed output columns)
// via sum/diff factorization (unchanged).
// ---------------------------------------------------------------------------
__global__ __launch_bounds__(256, 2) void k2(
        const float* __restrict__ out_base,
        const float* __restrict__ conv_w, const float* __restrict__ conv_b,
        float* __restrict__ out_smooth)
{
    __shared__ float2 sdl[199 * ANC];
    __shared__ float2 wael[ANC * ANC * KS];

    const int bidx = blockIdx.x;
    const int b  = bidx >> 3;
    const int ht = bidx & 7;
    const int h0 = ht * 125;
    const int t  = threadIdx.x;

    const float2* __restrict__ cw2 = reinterpret_cast<const float2*>(conv_w);
    for (int idx = t; idx < ANC * ANC * KS; idx += 256) {
        const float2 w = cw2[idx];
        wael[idx] = make_float2(w.x + w.y, w.x - w.y);
    }

    if (t < 199) {
        const int hglob = h0 - PADH + t;
        const int hm = hglob < 0 ? -hglob
                     : (hglob >= NWIN ? 2 * NWIN - 2 - hglob : hglob);
        float p[2][ANC];
#pragma unroll
        for (int c = 0; c < 2; ++c) {
            float v[ANC];
            float m = -1e30f;
#pragma unroll
            for (int a = 0; a < ANC; ++a) {
                v[a] = out_base[(((size_t)b * ANC + a) * NWIN + hm) * 2 + c];
                m = fmaxf(m, v[a]);
            }
            float s = 0.f;
#pragma unroll
            for (int a = 0; a < ANC; ++a) { v[a] = __expf(v[a] - m); s += v[a]; }
            const float inv = 1.f / s;
#pragma unroll
            for (int a = 0; a < ANC; ++a) p[c][a] = v[a] * inv;
        }
#pragma unroll
        for (int a = 0; a < ANC; ++a)
            sdl[t * ANC + a] = make_float2(p[0][a] + p[1][a], p[0][a] - p[1][a]);
    }
    __syncthreads();

    for (int idx = t; idx < ANC * 125; idx += 256) {
        const int o  = idx / 125;
        const int hl = idx % 125;
        float sa = 0.f, de = 0.f;
        const float2* __restrict__ wrow = &wael[o * ANC * KS];
#pragma unroll 1
        for (int i = 0; i < ANC; ++i) {
            const float2* __restrict__ sdp = &sdl[hl * ANC + i];
            const float2* __restrict__ wp  = &wrow[i * KS];
#pragma unroll 5
            for (int kh = 0; kh < KS; ++kh) {
                const float2 sd = sdp[kh * ANC];
                const float2 we = wp[kh];
                sa = fmaf(sd.x, we.x, sa);
                de = fmaf(sd.y, we.y, de);
            }
        }
        const float cb = conv_b[o];
        const float o0 = 0.5f * (sa - de) + cb;
        const float o1 = 0.5f * (sa + de) + cb;
        const size_t base = (((size_t)b * ANC + o) * NWIN + (h0 + hl)) * 2;
        out_smooth[base + 0] = o0;
        out_smooth[base + 1] = o1;
    }
}

extern "C" void kernel_launch(void* const* d_in, const int* in_sizes, int n_in,
                              void* d_out, int out_size, void* d_ws, size_t ws_size,
                              hipStream_t stream)
{
    const float* x      = (const float*)d_in[0];
    const float* W1     = (const float*)d_in[1];
    const float* b1     = (const float*)d_in[2];
    const float* W2     = (const float*)d_in[3];
    const float* b2     = (const float*)d_in[4];
    const float* conv_w = (const float*)d_in[5];
    const float* conv_b = (const float*)d_in[6];
    float* out = (float*)d_out;

    k1<<<dim3(NWIN), dim3(256), 0, stream>>>(x, W1, b1, W2, b2, out);
    k2<<<dim3(BATCH * 8), dim3(256), 0, stream>>>(out, conv_w, conv_b,
                                                  out + OBASE_ELEMS);
}